// Round 13
// baseline (118.574 us; speedup 1.0000x reference)
//
#include <hip/hip_runtime.h>

#define SP    65536      // 16*64*64 spatial voxels
#define DD    16
#define HH    64
#define WW    64
#define CIN   64
#define COUT  64

#define LOG2E 1.44269504f

// ws layout (fp32): q [64][SP] | k [64][SP] | v [64][SP]   (48 MB)
// LESSON LEDGER:
// r10: bf16 STORAGE of k fails accuracy. k stays fp32 in HBM.
// r11: bf16x3 split MFMA (wh*xh+wh*xl+wl*xh); q pre-scaled by LOG2E.
// r12: unbounded unroll of global loads -> hoist -> scratch spill.
// r14+r17: ANY min-waves launch_bounds on attn spills. attn runs uncapped.
// r16+r17: per-block in-register w split = proj regression; w-via-LDS kept.
// r19 DIAGNOSTIC: attn v10 = 24.3us wall.
// r21 LEDGER FIT (major): fill overhead is ~88us/iter (TWO ~44us poison
//   fills), not 44. Re-fit of all rounds: proj_v2(3-launch) ~= 3.4us (q/k/v
//   writes absorbed by L3 write-back; never HBM-serialized in-kernel);
//   attn_v10 = 24.3us is the ONLY remaining lever. splitw+merged-v7 = +2us
//   vs r8 -> reverted. rocprof replay dur is PMC-inflated ~2x (LDS kernels).
// r22: proj = r8's v2 verbatim. attn v12 = v10 flattened to a 9-row
// (kd,kh) loop with DEPTH-1 SOFTWARE PREFETCH (issue row r+1's k/v loads
// before computing row r; named-register rotation, static indices, no
// arrays -> no spill path). Row order preserved -> bit-identical FP order;
// absmax must stay exactly 0.015625.
// r23 (this): r22 RESUBMITTED VERBATIM - bench failed on container
// infrastructure ("MI355X container failed twice"), not on the kernel.

typedef __attribute__((ext_vector_type(8))) short bf16x8;   // 8 bf16 = 4 VGPRs
typedef __attribute__((ext_vector_type(4))) float f32x4;    // MFMA acc

__device__ __forceinline__ unsigned short f2bf(float f) {   // RNE f32->bf16
    const unsigned u = __float_as_uint(f);
    return (unsigned short)((u + 0x7FFFu + ((u >> 16) & 1u)) >> 16);
}
__device__ __forceinline__ float bf2f(unsigned short h) {
    return __uint_as_float((unsigned)h << 16);
}

// proj v2 (r8 verbatim, 3.4us by ledger): per block 64 positions x all 64
// outs, one matrix (grid.y); 3072 blocks. K=64 in LDS once. x staged
// TRANSPOSED [j][c] hi/lo; w staged [o][c] hi/lo VIA LDS. A/B both pack 8
// consecutive cin -> same k-permutation both operands -> layout-safe.
// C/D layout (HW-verified): col=lane&15, row=(lane>>4)*4+reg.
__global__ __launch_bounds__(256) void proj(const float* __restrict__ x,
                                            const float* __restrict__ wq,
                                            const float* __restrict__ wk,
                                            const float* __restrict__ wv,
                                            float* __restrict__ q,
                                            float* __restrict__ k,
                                            float* __restrict__ v) {
    __shared__ __align__(16) unsigned short xh [64][72];   // [j][c] hi, 9 KB
    __shared__ __align__(16) unsigned short xlo[64][72];   // [j][c] lo
    __shared__ __align__(16) unsigned short wh [64][72];   // [o][c] hi
    __shared__ __align__(16) unsigned short wlo[64][72];   // 36.9 KB -> 4 blk/CU

    const int t  = threadIdx.x;
    const int p0 = blockIdx.x * 64;
    const int m  = blockIdx.y;

    const float* __restrict__ wsel = (m == 0) ? wq : (m == 1) ? wk : wv;
    float* __restrict__       osel = (m == 0) ? q  : (m == 1) ? k  : v;

#pragma unroll
    for (int i = 0; i < 2; ++i) {
        const int f  = t + 256 * i;          // 0..511
        const int c2 = (f >> 4) * 2;
        const int jj = f & 15;
        const float4 a = *(const float4*)(x + c2 * SP + p0 + jj * 4);
        const float4 b = *(const float4*)(x + (c2 + 1) * SP + p0 + jj * 4);
        const float* af = (const float*)&a;
        const float* bf = (const float*)&b;
#pragma unroll
        for (int e = 0; e < 4; ++e) {
            const int j = jj * 4 + e;
            const unsigned short ah = f2bf(af[e]);
            const unsigned short bh = f2bf(bf[e]);
            const unsigned short al = f2bf(af[e] - bf2f(ah));
            const unsigned short bl = f2bf(bf[e] - bf2f(bh));
            *(unsigned*)&xh [j][c2] = (unsigned)ah | ((unsigned)bh << 16);
            *(unsigned*)&xlo[j][c2] = (unsigned)al | ((unsigned)bl << 16);
        }
    }
#pragma unroll
    for (int i = 0; i < 4; ++i) {
        const int f  = t + 256 * i;          // 0..1023
        const int o  = f >> 4;
        const int jj = f & 15;
        const float4 w4 = *(const float4*)(wsel + o * CIN + jj * 4);
        const float* wf = (const float*)&w4;
        unsigned short h0 = f2bf(wf[0]), h1 = f2bf(wf[1]);
        unsigned short h2 = f2bf(wf[2]), h3 = f2bf(wf[3]);
        unsigned short l0 = f2bf(wf[0] - bf2f(h0)), l1 = f2bf(wf[1] - bf2f(h1));
        unsigned short l2 = f2bf(wf[2] - bf2f(h2)), l3 = f2bf(wf[3] - bf2f(h3));
        *(uint2*)&wh [o][jj * 4] = make_uint2((unsigned)h0 | ((unsigned)h1 << 16),
                                              (unsigned)h2 | ((unsigned)h3 << 16));
        *(uint2*)&wlo[o][jj * 4] = make_uint2((unsigned)l0 | ((unsigned)l1 << 16),
                                              (unsigned)l2 | ((unsigned)l3 << 16));
    }
    __syncthreads();

    const int lane  = t & 63;
    const int wid   = t >> 6;                // wave -> 16-out slice
    const int lo16  = lane & 15;
    const int lg    = lane >> 4;             // 0..3 k-group
    const int otile = wid * 16;

    const bf16x8 Ah0 = *(const bf16x8*)&wh [otile + lo16][lg * 8];
    const bf16x8 Ah1 = *(const bf16x8*)&wh [otile + lo16][32 + lg * 8];
    const bf16x8 Al0 = *(const bf16x8*)&wlo[otile + lo16][lg * 8];
    const bf16x8 Al1 = *(const bf16x8*)&wlo[otile + lo16][32 + lg * 8];

    const float scale = (m == 0) ? LOG2E : 1.f;   // fold exp2 prescale into q

#pragma unroll
    for (int jt = 0; jt < 4; ++jt) {
        const int jr = jt * 16 + lo16;
        const bf16x8 Bh0 = *(const bf16x8*)&xh [jr][lg * 8];
        const bf16x8 Bl0 = *(const bf16x8*)&xlo[jr][lg * 8];
        const bf16x8 Bh1 = *(const bf16x8*)&xh [jr][32 + lg * 8];
        const bf16x8 Bl1 = *(const bf16x8*)&xlo[jr][32 + lg * 8];
        f32x4 hh = {0.f, 0.f, 0.f, 0.f};     // 3 independent chains for ILP
        f32x4 hl = {0.f, 0.f, 0.f, 0.f};
        f32x4 lh = {0.f, 0.f, 0.f, 0.f};
        hh = __builtin_amdgcn_mfma_f32_16x16x32_bf16(Ah0, Bh0, hh, 0, 0, 0);
        hl = __builtin_amdgcn_mfma_f32_16x16x32_bf16(Ah0, Bl0, hl, 0, 0, 0);
        lh = __builtin_amdgcn_mfma_f32_16x16x32_bf16(Al0, Bh0, lh, 0, 0, 0);
        hh = __builtin_amdgcn_mfma_f32_16x16x32_bf16(Ah1, Bh1, hh, 0, 0, 0);
        hl = __builtin_amdgcn_mfma_f32_16x16x32_bf16(Ah1, Bl1, hl, 0, 0, 0);
        lh = __builtin_amdgcn_mfma_f32_16x16x32_bf16(Al1, Bh1, lh, 0, 0, 0);
        float* op = osel + (otile + lg * 4) * SP + p0 + jt * 16 + lo16;
#pragma unroll
        for (int r = 0; r < 4; ++r)
            op[r * SP] = (hh[r] + hl[r] + lh[r]) * scale;   // 4 rows x 64B, coalesced
    }
}

// DPP shifts within 16-lane rows; bound_ctrl=1 -> out-of-row reads 0 =
// exactly the w-boundary zero-pad.
__device__ __forceinline__ float dpp_shr1(float x) {   // lane i <- lane i-1
    return __int_as_float(__builtin_amdgcn_mov_dpp(__float_as_int(x), 0x111, 0xf, 0xf, true));
}
__device__ __forceinline__ float dpp_shl1(float x) {   // lane i <- lane i+1
    return __int_as_float(__builtin_amdgcn_mov_dpp(__float_as_int(x), 0x101, 0xf, 0xf, true));
}

// attn v12 walk: 9 (kd,kh) rows flattened, depth-1 software prefetch.
// Row order = v10's (kd outer, kh inner) -> bit-identical accumulation.
// kd/kh are wave-uniform scalar counters (s_cselect rel picks).
// OOB rows: address clamped to 0, value zeroed (k=0 -> exp(q*rel), v=0).
template<int AXIS>
__device__ __forceinline__ void attn_walk(const float* __restrict__ kc,
                                          const float* __restrict__ vc,
                                          const float (&ql)[4],
                                          float r0, float r1, float r2,
                                          int wg, int dabs, int habs,
                                          float (&s)[4], float (&a)[4]) {
    const int base = wg * 4;

    int kd = 0, kh = 0;
    bool okc;
    float4 kmc, vmc;
    {   // preload row (0,0)
        const int dpg = dabs - 1;
        const int hpg = habs - 1;
        okc = ((unsigned)dpg < (unsigned)DD) && ((unsigned)hpg < (unsigned)HH);
        const int off = okc ? ((dpg * HH + hpg) * WW + base) : 0;
        kmc = *(const float4*)(kc + off);
        vmc = *(const float4*)(vc + off);
    }

#pragma unroll 1
    for (int r = 0; r < 9; ++r) {
        // ---- issue NEXT row's loads (depth-1 prefetch) ----
        const int kh2 = (kh == 2) ? 0 : kh + 1;
        const int kd2 = (kh == 2) ? kd + 1 : kd;
        float4 kmn = make_float4(0.f, 0.f, 0.f, 0.f);
        float4 vmn = make_float4(0.f, 0.f, 0.f, 0.f);
        bool okn = false;
        if (r < 8) {                       // wave-uniform branch
            const int dpg = dabs - 1 + kd2;
            const int hpg = habs - 1 + kh2;
            okn = ((unsigned)dpg < (unsigned)DD) && ((unsigned)hpg < (unsigned)HH);
            const int off = okn ? ((dpg * HH + hpg) * WW + base) : 0;
            kmn = *(const float4*)(kc + off);
            vmn = *(const float4*)(vc + off);
        }

        // ---- compute CURRENT row ----
        float4 km = kmc, vm = vmc;
        if (!okc) {
            km = make_float4(0.f, 0.f, 0.f, 0.f);
            vm = make_float4(0.f, 0.f, 0.f, 0.f);
        }
        const float rdd = (kd == 0) ? r0 : (kd == 1) ? r1 : r2;   // s_cselect
        const float rkh = (kh == 0) ? r0 : (kh == 1) ? r1 : r2;
        const float rr  = (AXIS == 0) ? rdd : rkh;

        const float kl = dpp_shr1(km.w), kr = dpp_shl1(km.x);
        const float vl = dpp_shr1(vm.w), vr = dpp_shl1(vm.x);
        float krow[6] = { kl, km.x, km.y, km.z, km.w, kr };
        const float vrow[6] = { vl, vm.x, vm.y, vm.z, vm.w, vr };
        if (AXIS != 2) {                   // hoist row-constant rel
#pragma unroll
            for (int j = 0; j < 6; ++j) krow[j] += rr;
        }
#pragma unroll
        for (int wi = 0; wi < 4; ++wi) {
            const float qv = ql[wi];
#pragma unroll
            for (int kw = 0; kw < 3; ++kw) {
                const float arg = (AXIS == 2)
                                ? (krow[wi + kw] + ((kw == 0) ? r0 : (kw == 1) ? r1 : r2))
                                : krow[wi + kw];
                const float e = __builtin_amdgcn_exp2f(qv * arg);
                s[wi] += e;
                a[wi] = fmaf(e, vrow[wi + kw], a[wi]);
            }
        }

        // ---- rotate pipeline ----
        kmc = kmn; vmc = vmn; okc = okn;
        kd = kd2; kh = kh2;
    }
}

// attn v12: block = (dtile4 x htile4, o); thread = ONE float4 (1d x 4w).
// NO LDS, NO barrier, no launch_bounds cap (r14/r17). Single-pass softmax.
__global__ __launch_bounds__(256) void attn(const float* __restrict__ kbuf,
                                            const float* __restrict__ vbuf,
                                            const float* __restrict__ qbuf,
                                            const float* __restrict__ rel_d,
                                            const float* __restrict__ rel_h,
                                            const float* __restrict__ rel_w,
                                            float* __restrict__ out) {
    const int dt = blockIdx.x;       // 0..3
    const int ht = blockIdx.y;       // 0..15
    const int o  = blockIdx.z;       // 0..63

    const int d0 = dt * 4;
    const int h0 = ht * 4;
    const int t  = threadIdx.x;

    const float* __restrict__ kc = kbuf + o * SP;
    const float* __restrict__ vc = vbuf + o * SP;

    const int wg = t & 15;           // float4 in w
    const int hl = (t >> 4) & 3;     // local h
    const int dl = t >> 6;           // local d (== wave id)

    const int dabs = d0 + dl;
    const int habs = h0 + hl;

    float ql[4];
    {
        const float4 q4 = *(const float4*)(qbuf + o * SP + (dabs * HH + habs) * WW + wg * 4);
        ql[0] = q4.x; ql[1] = q4.y;            // q pre-scaled by LOG2E in proj
        ql[2] = q4.z; ql[3] = q4.w;
    }

    float s[4] = {};
    float a[4] = {};

    if (o < 21) {
        attn_walk<0>(kc, vc, ql, rel_d[o * 3], rel_d[o * 3 + 1], rel_d[o * 3 + 2],
                     wg, dabs, habs, s, a);
    } else if (o < 42) {
        const int b = o - 21;
        attn_walk<1>(kc, vc, ql, rel_h[b * 3], rel_h[b * 3 + 1], rel_h[b * 3 + 2],
                     wg, dabs, habs, s, a);
    } else {
        const int b = o - 42;
        attn_walk<2>(kc, vc, ql, rel_w[b * 3], rel_w[b * 3 + 1], rel_w[b * 3 + 2],
                     wg, dabs, habs, s, a);
    }

    float4 ov;
    ov.x = a[0] * __builtin_amdgcn_rcpf(s[0]);
    ov.y = a[1] * __builtin_amdgcn_rcpf(s[1]);
    ov.z = a[2] * __builtin_amdgcn_rcpf(s[2]);
    ov.w = a[3] * __builtin_amdgcn_rcpf(s[3]);
    *(float4*)(out + o * SP + (dabs * HH + habs) * WW + wg * 4) = ov;
}

extern "C" void kernel_launch(void* const* d_in, const int* in_sizes, int n_in,
                              void* d_out, int out_size, void* d_ws, size_t ws_size,
                              hipStream_t stream) {
    const float* x     = (const float*)d_in[0];
    const float* w_q   = (const float*)d_in[1];
    const float* w_k   = (const float*)d_in[2];
    const float* w_v   = (const float*)d_in[3];
    const float* rel_d = (const float*)d_in[4];
    const float* rel_h = (const float*)d_in[5];
    const float* rel_w = (const float*)d_in[6];
    float* out = (float*)d_out;

    float* ws = (float*)d_ws;
    float* q  = ws;
    float* k  = ws + (size_t)COUT * SP;
    float* v  = ws + 2 * (size_t)COUT * SP;

    proj<<<dim3(SP / 64, 3), 256, 0, stream>>>(x, w_q, w_k, w_v, q, k, v);
    attn<<<dim3(4, 16, 64), 256, 0, stream>>>(k, v, q, rel_d, rel_h, rel_w, out);
}

// Round 14
// 115.860 us; speedup vs baseline: 1.0234x; 1.0234x over previous
//
#include <hip/hip_runtime.h>

#define SP    65536      // 16*64*64 spatial voxels
#define DD    16
#define HH    64
#define WW    64
#define CIN   64
#define COUT  64

#define LOG2E 1.44269504f

// ws layout (fp32): q [64][SP] | k [64][SP] | v [64][SP]   (48 MB)
// LESSON LEDGER:
// r10: bf16 STORAGE of k fails accuracy. k stays fp32 in HBM.
// r11: bf16x3 split MFMA (wh*xh+wh*xl+wl*xh); q pre-scaled by LOG2E.
// r12: unbounded unroll of global loads -> hoist -> scratch spill.
// r14+r17: ANY min-waves launch_bounds on attn spills. attn runs uncapped.
// r16+r17: per-block in-register w split = proj regression; w-via-LDS kept.
// r19 DIAGNOSTIC: attn v10 = 24.3us wall.
// r21 LEDGER FIT: fill overhead ~88us/iter (two ~44us poison fills).
//   proj_v2(3-launch) ~= 3.4us; attn is the only lever. rocprof replay
//   dur is PMC-inflated ~2x for LDS kernels.
// r22/r23: depth-1 prefetch attn v12 = NULL (118.6 vs 115.7, within noise).
//   Reverted to v10.
// r24 (this): T1 XCD-aware bijective swizzle on attn's grid (m204 form,
// 4096%8==0 -> exact). Old grid round-robins adjacent (dt,ht) tiles across
// XCDs -> 6x6-halo re-reads (2.25x k/v amplification, r7: FETCH 77MB vs
// 50.3 compulsory) miss the neighbor's L2. New map: each XCD owns 8
// consecutive channels; all 64 tiles of a channel dispatch together on one
// XCD -> 1MB k+v slab L2-resident -> halo re-reads L2-hit. Pure index
// remap; arithmetic unchanged; absmax must stay exactly 0.015625.

typedef __attribute__((ext_vector_type(8))) short bf16x8;   // 8 bf16 = 4 VGPRs
typedef __attribute__((ext_vector_type(4))) float f32x4;    // MFMA acc

__device__ __forceinline__ unsigned short f2bf(float f) {   // RNE f32->bf16
    const unsigned u = __float_as_uint(f);
    return (unsigned short)((u + 0x7FFFu + ((u >> 16) & 1u)) >> 16);
}
__device__ __forceinline__ float bf2f(unsigned short h) {
    return __uint_as_float((unsigned)h << 16);
}

// proj v2 (r8 verbatim, ~3.4us by ledger): per block 64 positions x all 64
// outs, one matrix (grid.y); 3072 blocks. K=64 in LDS once. x staged
// TRANSPOSED [j][c] hi/lo; w staged [o][c] hi/lo VIA LDS. A/B both pack 8
// consecutive cin -> same k-permutation both operands -> layout-safe.
// C/D layout (HW-verified): col=lane&15, row=(lane>>4)*4+reg.
__global__ __launch_bounds__(256) void proj(const float* __restrict__ x,
                                            const float* __restrict__ wq,
                                            const float* __restrict__ wk,
                                            const float* __restrict__ wv,
                                            float* __restrict__ q,
                                            float* __restrict__ k,
                                            float* __restrict__ v) {
    __shared__ __align__(16) unsigned short xh [64][72];   // [j][c] hi, 9 KB
    __shared__ __align__(16) unsigned short xlo[64][72];   // [j][c] lo
    __shared__ __align__(16) unsigned short wh [64][72];   // [o][c] hi
    __shared__ __align__(16) unsigned short wlo[64][72];   // 36.9 KB -> 4 blk/CU

    const int t  = threadIdx.x;
    const int p0 = blockIdx.x * 64;
    const int m  = blockIdx.y;

    const float* __restrict__ wsel = (m == 0) ? wq : (m == 1) ? wk : wv;
    float* __restrict__       osel = (m == 0) ? q  : (m == 1) ? k  : v;

#pragma unroll
    for (int i = 0; i < 2; ++i) {
        const int f  = t + 256 * i;          // 0..511
        const int c2 = (f >> 4) * 2;
        const int jj = f & 15;
        const float4 a = *(const float4*)(x + c2 * SP + p0 + jj * 4);
        const float4 b = *(const float4*)(x + (c2 + 1) * SP + p0 + jj * 4);
        const float* af = (const float*)&a;
        const float* bf = (const float*)&b;
#pragma unroll
        for (int e = 0; e < 4; ++e) {
            const int j = jj * 4 + e;
            const unsigned short ah = f2bf(af[e]);
            const unsigned short bh = f2bf(bf[e]);
            const unsigned short al = f2bf(af[e] - bf2f(ah));
            const unsigned short bl = f2bf(bf[e] - bf2f(bh));
            *(unsigned*)&xh [j][c2] = (unsigned)ah | ((unsigned)bh << 16);
            *(unsigned*)&xlo[j][c2] = (unsigned)al | ((unsigned)bl << 16);
        }
    }
#pragma unroll
    for (int i = 0; i < 4; ++i) {
        const int f  = t + 256 * i;          // 0..1023
        const int o  = f >> 4;
        const int jj = f & 15;
        const float4 w4 = *(const float4*)(wsel + o * CIN + jj * 4);
        const float* wf = (const float*)&w4;
        unsigned short h0 = f2bf(wf[0]), h1 = f2bf(wf[1]);
        unsigned short h2 = f2bf(wf[2]), h3 = f2bf(wf[3]);
        unsigned short l0 = f2bf(wf[0] - bf2f(h0)), l1 = f2bf(wf[1] - bf2f(h1));
        unsigned short l2 = f2bf(wf[2] - bf2f(h2)), l3 = f2bf(wf[3] - bf2f(h3));
        *(uint2*)&wh [o][jj * 4] = make_uint2((unsigned)h0 | ((unsigned)h1 << 16),
                                              (unsigned)h2 | ((unsigned)h3 << 16));
        *(uint2*)&wlo[o][jj * 4] = make_uint2((unsigned)l0 | ((unsigned)l1 << 16),
                                              (unsigned)l2 | ((unsigned)l3 << 16));
    }
    __syncthreads();

    const int lane  = t & 63;
    const int wid   = t >> 6;                // wave -> 16-out slice
    const int lo16  = lane & 15;
    const int lg    = lane >> 4;             // 0..3 k-group
    const int otile = wid * 16;

    const bf16x8 Ah0 = *(const bf16x8*)&wh [otile + lo16][lg * 8];
    const bf16x8 Ah1 = *(const bf16x8*)&wh [otile + lo16][32 + lg * 8];
    const bf16x8 Al0 = *(const bf16x8*)&wlo[otile + lo16][lg * 8];
    const bf16x8 Al1 = *(const bf16x8*)&wlo[otile + lo16][32 + lg * 8];

    const float scale = (m == 0) ? LOG2E : 1.f;   // fold exp2 prescale into q

#pragma unroll
    for (int jt = 0; jt < 4; ++jt) {
        const int jr = jt * 16 + lo16;
        const bf16x8 Bh0 = *(const bf16x8*)&xh [jr][lg * 8];
        const bf16x8 Bl0 = *(const bf16x8*)&xlo[jr][lg * 8];
        const bf16x8 Bh1 = *(const bf16x8*)&xh [jr][32 + lg * 8];
        const bf16x8 Bl1 = *(const bf16x8*)&xlo[jr][32 + lg * 8];
        f32x4 hh = {0.f, 0.f, 0.f, 0.f};     // 3 independent chains for ILP
        f32x4 hl = {0.f, 0.f, 0.f, 0.f};
        f32x4 lh = {0.f, 0.f, 0.f, 0.f};
        hh = __builtin_amdgcn_mfma_f32_16x16x32_bf16(Ah0, Bh0, hh, 0, 0, 0);
        hl = __builtin_amdgcn_mfma_f32_16x16x32_bf16(Ah0, Bl0, hl, 0, 0, 0);
        lh = __builtin_amdgcn_mfma_f32_16x16x32_bf16(Al0, Bh0, lh, 0, 0, 0);
        hh = __builtin_amdgcn_mfma_f32_16x16x32_bf16(Ah1, Bh1, hh, 0, 0, 0);
        hl = __builtin_amdgcn_mfma_f32_16x16x32_bf16(Ah1, Bl1, hl, 0, 0, 0);
        lh = __builtin_amdgcn_mfma_f32_16x16x32_bf16(Al1, Bh1, lh, 0, 0, 0);
        float* op = osel + (otile + lg * 4) * SP + p0 + jt * 16 + lo16;
#pragma unroll
        for (int r = 0; r < 4; ++r)
            op[r * SP] = (hh[r] + hl[r] + lh[r]) * scale;   // 4 rows x 64B, coalesced
    }
}

// DPP shifts within 16-lane rows; bound_ctrl=1 -> out-of-row reads 0 =
// exactly the w-boundary zero-pad.
__device__ __forceinline__ float dpp_shr1(float x) {   // lane i <- lane i-1
    return __int_as_float(__builtin_amdgcn_mov_dpp(__float_as_int(x), 0x111, 0xf, 0xf, true));
}
__device__ __forceinline__ float dpp_shl1(float x) {   // lane i <- lane i+1
    return __int_as_float(__builtin_amdgcn_mov_dpp(__float_as_int(x), 0x101, 0xf, 0xf, true));
}

// attn v10 walk (r18/r19 form, 24.3us measured): thread = 1 float4 output;
// 9 (kd,kh) rows read DIRECTLY from global. unroll(1) on kd bounds loads.
// OOB rows: address clamped to 0, value zeroed (k=0 -> exp(q*rel), v=0).
template<int AXIS>
__device__ __forceinline__ void attn_walk(const float* __restrict__ kc,
                                          const float* __restrict__ vc,
                                          const float (&ql)[4],
                                          float r0, float r1, float r2,
                                          int wg, int dabs, int habs,
                                          float (&s)[4], float (&a)[4]) {
#pragma unroll 1
    for (int kd = 0; kd < 3; ++kd) {
        const float rdd = (kd == 0) ? r0 : (kd == 1) ? r1 : r2;
        const int dpg   = dabs - 1 + kd;
        const bool okd  = (unsigned)dpg < (unsigned)DD;
#pragma unroll
        for (int kh = 0; kh < 3; ++kh) {
            const float rkh = (kh == 0) ? r0 : (kh == 1) ? r1 : r2;
            const float rr  = (AXIS == 0) ? rdd : rkh;
            const int hpg   = habs - 1 + kh;
            const bool ok   = okd && ((unsigned)hpg < (unsigned)HH);
            const int off   = ok ? ((dpg * HH + hpg) * WW + wg * 4) : 0;
            float4 km = *(const float4*)(kc + off);
            float4 vm = *(const float4*)(vc + off);
            if (!ok) {
                km = make_float4(0.f, 0.f, 0.f, 0.f);
                vm = make_float4(0.f, 0.f, 0.f, 0.f);
            }
            const float kl = dpp_shr1(km.w), kr = dpp_shl1(km.x);
            const float vl = dpp_shr1(vm.w), vr = dpp_shl1(vm.x);
            float krow[6] = { kl, km.x, km.y, km.z, km.w, kr };
            const float vrow[6] = { vl, vm.x, vm.y, vm.z, vm.w, vr };
            if (AXIS != 2) {                 // hoist row-constant rel
#pragma unroll
                for (int j = 0; j < 6; ++j) krow[j] += rr;
            }
#pragma unroll
            for (int wi = 0; wi < 4; ++wi) {
                const float qv = ql[wi];
#pragma unroll
                for (int kw = 0; kw < 3; ++kw) {
                    const float arg = (AXIS == 2)
                                    ? (krow[wi + kw] + ((kw == 0) ? r0 : (kw == 1) ? r1 : r2))
                                    : krow[wi + kw];
                    const float e = __builtin_amdgcn_exp2f(qv * arg);
                    s[wi] += e;
                    a[wi] = fmaf(e, vrow[wi + kw], a[wi]);
                }
            }
        }
    }
}

// attn v13: v10 body + T1 XCD-aware bijective grid swizzle. 1-D grid 4096.
// xcd = bid&7 (dispatch round-robin); lin = xcd*512 + bid/8 -> XCD c owns
// channels [c*8, c*8+8): all 64 (dt,ht) tiles of a channel run on one XCD,
// k+v slab (1MB) L2-resident -> halo re-reads L2-hit.
// NO LDS, NO barrier, no launch_bounds cap (r14/r17). Single-pass softmax.
__global__ __launch_bounds__(256) void attn(const float* __restrict__ kbuf,
                                            const float* __restrict__ vbuf,
                                            const float* __restrict__ qbuf,
                                            const float* __restrict__ rel_d,
                                            const float* __restrict__ rel_h,
                                            const float* __restrict__ rel_w,
                                            float* __restrict__ out) {
    const int bid = blockIdx.x;      // 0..4095
    const int lin = (bid & 7) * 512 + (bid >> 3);   // bijective (4096%8==0)
    const int o   = lin >> 6;        // 0..63
    const int rem = lin & 63;
    const int ht  = rem >> 2;        // 0..15
    const int dt  = rem & 3;         // 0..3

    const int d0 = dt * 4;
    const int h0 = ht * 4;
    const int t  = threadIdx.x;

    const float* __restrict__ kc = kbuf + o * SP;
    const float* __restrict__ vc = vbuf + o * SP;

    const int wg = t & 15;           // float4 in w
    const int hl = (t >> 4) & 3;     // local h
    const int dl = t >> 6;           // local d (== wave id)

    const int dabs = d0 + dl;
    const int habs = h0 + hl;

    float ql[4];
    {
        const float4 q4 = *(const float4*)(qbuf + o * SP + (dabs * HH + habs) * WW + wg * 4);
        ql[0] = q4.x; ql[1] = q4.y;            // q pre-scaled by LOG2E in proj
        ql[2] = q4.z; ql[3] = q4.w;
    }

    float s[4] = {};
    float a[4] = {};

    if (o < 21) {
        attn_walk<0>(kc, vc, ql, rel_d[o * 3], rel_d[o * 3 + 1], rel_d[o * 3 + 2],
                     wg, dabs, habs, s, a);
    } else if (o < 42) {
        const int b = o - 21;
        attn_walk<1>(kc, vc, ql, rel_h[b * 3], rel_h[b * 3 + 1], rel_h[b * 3 + 2],
                     wg, dabs, habs, s, a);
    } else {
        const int b = o - 42;
        attn_walk<2>(kc, vc, ql, rel_w[b * 3], rel_w[b * 3 + 1], rel_w[b * 3 + 2],
                     wg, dabs, habs, s, a);
    }

    float4 ov;
    ov.x = a[0] * __builtin_amdgcn_rcpf(s[0]);
    ov.y = a[1] * __builtin_amdgcn_rcpf(s[1]);
    ov.z = a[2] * __builtin_amdgcn_rcpf(s[2]);
    ov.w = a[3] * __builtin_amdgcn_rcpf(s[3]);
    *(float4*)(out + o * SP + (dabs * HH + habs) * WW + wg * 4) = ov;
}

extern "C" void kernel_launch(void* const* d_in, const int* in_sizes, int n_in,
                              void* d_out, int out_size, void* d_ws, size_t ws_size,
                              hipStream_t stream) {
    const float* x     = (const float*)d_in[0];
    const float* w_q   = (const float*)d_in[1];
    const float* w_k   = (const float*)d_in[2];
    const float* w_v   = (const float*)d_in[3];
    const float* rel_d = (const float*)d_in[4];
    const float* rel_h = (const float*)d_in[5];
    const float* rel_w = (const float*)d_in[6];
    float* out = (float*)d_out;

    float* ws = (float*)d_ws;
    float* q  = ws;
    float* k  = ws + (size_t)COUT * SP;
    float* v  = ws + 2 * (size_t)COUT * SP;

    proj<<<dim3(SP / 64, 3), 256, 0, stream>>>(x, w_q, w_k, w_v, q, k, v);
    attn<<<dim3(4096), 256, 0, stream>>>(k, v, q, rel_d, rel_h, rel_w, out);
}